// Round 10
// baseline (126.929 us; speedup 1.0000x reference)
//
#include <hip/hip_runtime.h>
#include <hip/hip_bf16.h>

#define LN_EPS 1e-5f
#define S2LE 2.885390081777927f   // 2*log2(e)
#define L2E  1.4426950408889634f  // log2(e)
#define XST 68                    // LDS row stride for x tile (16B-aligned rows)

typedef __attribute__((ext_vector_type(8))) short bf16x8;
typedef __attribute__((ext_vector_type(4))) float f32x4;

__device__ __forceinline__ float wsum(float v) {
    #pragma unroll
    for (int off = 32; off; off >>= 1) v += __shfl_xor(v, off, 64);
    return v;
}
__device__ __forceinline__ float wmax(float v) {
    #pragma unroll
    for (int off = 32; off; off >>= 1) v = fmaxf(v, __shfl_xor(v, off, 64));
    return v;
}
// 8x f32 -> bf16 (RNE) via v_cvt_pk_bf16_f32
__device__ __forceinline__ bf16x8 pack8(float4 a, float4 b) {
    __hip_bfloat162 h0 = __float22bfloat162_rn(float2{a.x, a.y});
    __hip_bfloat162 h1 = __float22bfloat162_rn(float2{a.z, a.w});
    __hip_bfloat162 h2 = __float22bfloat162_rn(float2{b.x, b.y});
    __hip_bfloat162 h3 = __float22bfloat162_rn(float2{b.z, b.w});
    short2 s0 = *reinterpret_cast<short2*>(&h0);
    short2 s1 = *reinterpret_cast<short2*>(&h1);
    short2 s2 = *reinterpret_cast<short2*>(&h2);
    short2 s3 = *reinterpret_cast<short2*>(&h3);
    bf16x8 r;
    r[0] = s0.x; r[1] = s0.y; r[2] = s1.x; r[3] = s1.y;
    r[4] = s2.x; r[5] = s2.y; r[6] = s3.x; r[7] = s3.y;
    return r;
}
__device__ __forceinline__ float fexp2(float x) {
#if __has_builtin(__builtin_amdgcn_exp2f)
    return __builtin_amdgcn_exp2f(x);
#else
    return exp2f(x);
#endif
}
__device__ __forceinline__ float frcp(float x) {
#if __has_builtin(__builtin_amdgcn_rcpf)
    return __builtin_amdgcn_rcpf(x);
#else
    return 1.f / x;
#endif
}

// ================= prep: 513 blocks x 256 threads, roles by blockIdx =================
// blocks 0..255   : ai/aj (32 rows each), prescaled by S2LE
// blocks 256..511 : afrag pack (4 fragment-slots per block)
// block 512       : Tf' = g*Wij - S/64 (A-frag order), c2, consts[0]=sum(W2)+b2,
//                   consts[16+d] = -2*W2[d]
__global__ __launch_bounds__(256) void att1_prep(
    const float* __restrict__ emb, const float* __restrict__ g,
    const float* __restrict__ bln, const float* __restrict__ W1,
    const float* __restrict__ b1, const float* __restrict__ W2,
    const float* __restrict__ b2, float* __restrict__ ai,
    float* __restrict__ aj, short* __restrict__ afrag,
    float* __restrict__ Tf, float* __restrict__ c2, float* __restrict__ consts)
{
    const int bid = blockIdx.x, tid = threadIdx.x, lane = tid & 63, wid = tid >> 6;
    if (bid < 256) {
        __shared__ float w_s[8192];
        __shared__ float xn_s[4][64];
        for (int i = tid * 4; i < 8192; i += 1024)
            *(float4*)&w_s[i] = *(const float4*)&W1[i];
        __syncthreads();
        #pragma unroll 2
        for (int it = 0; it < 8; ++it) {
            const int r = bid * 32 + it * 4 + wid;
            float x = emb[r * 64 + lane];
            float m = wsum(x) * (1.f / 64.f);
            float xc = x - m;
            float var = wsum(xc * xc) * (1.f / 64.f);
            float xn = xc * rsqrtf(var + LN_EPS) * g[lane] + bln[lane];
            xn_s[wid][lane] = xn;          // same-wave write->read
            float a0 = 0.f, a1 = 0.f;
            #pragma unroll
            for (int k = 0; k < 64; ++k) {
                float xnk = xn_s[wid][k];
                a0 = fmaf(xnk, w_s[k * 64 + lane], a0);
                a1 = fmaf(xnk, w_s[(64 + k) * 64 + lane], a1);
            }
            ai[r * 64 + lane] = a0 * S2LE;
            aj[r * 64 + lane] = a1 * S2LE;
        }
    } else if (bid < 512) {
        const int id = (bid - 256) * 4 + wid;      // b*16 + qt*2 + h
        const int h = id & 1, qt = (id >> 1) & 7, bb = id >> 4;
        const int q = 16 * qt + (lane & 15);
        const int k = 32 * h + 8 * (lane >> 4);
        const float* src = emb + (bb * 128 + q) * 64 + k;
        float4 v0 = ((const float4*)src)[0];
        float4 v1 = ((const float4*)src)[1];
        *(bf16x8*)(afrag + (size_t)(id * 64 + lane) * 8) = pack8(v0, v1);
    } else {
        __shared__ float S_s[64];
        if (tid < 64) {
            float S = 0.f, c = 0.f;
            for (int k = 0; k < 64; ++k) {
                float w = W1[(128 + k) * 64 + tid];
                S = fmaf(g[k], w, S);
                c = fmaf(bln[k], w, c);
            }
            S_s[tid] = S * (1.f / 64.f);
            c2[tid] = (c + b1[tid]) * S2LE;
            consts[16 + tid] = -2.f * W2[tid];
            if (tid == 0) {
                float sw = 0.f;
                for (int d = 0; d < 64; ++d) sw += W2[d];
                consts[0] = sw + b2[0];
            }
        }
        __syncthreads();
        for (int slot = tid; slot < 512; slot += 256) {   // (dt*2+h)*64 + l
            int l = slot & 63, h = (slot >> 6) & 1, dt = slot >> 7;
            int n = 16 * dt + (l & 15);                   // A-frag row = d
            int k = 32 * h + 8 * (l >> 4);
            float Sn = S_s[n];                            // S[d]/64
            #pragma unroll
            for (int j = 0; j < 8; ++j)
                Tf[slot * 8 + j] = fmaf(g[k + j], W1[(128 + k + j) * 64 + n], -Sn);
        }
    }
}

// per-dt epilogue quad: pr += sum_r w2[r] / (2^xv + 1) terms
__device__ __forceinline__ float epi4(f32x4 acc, float rsv, const float* aiq,
                                      const float* ajcW, const float* w2g,
                                      int off, float pr) {
    float4 ajc4 = *(const float4*)(ajcW + off);
    float4 w24  = *(const float4*)(w2g + off);
    float4 aif  = *(const float4*)aiq;
    float ajcv[4] = {ajc4.x, ajc4.y, ajc4.z, ajc4.w};
    float w2v[4]  = {w24.x, w24.y, w24.z, w24.w};
    float aiv[4]  = {aif.x, aif.y, aif.z, aif.w};
    #pragma unroll
    for (int r = 0; r < 4; ++r) {
        float xv = fmaf(rsv, acc[r], ajcv[r] + aiv[r]);
        float e = fexp2(xv);
        pr = fmaf(w2v[r], frcp(e + 1.f), pr);
    }
    return pr;
}

// ================= main: block = (b, 8 p's), 512 thr; wave w owns p = 8*bx + w.
// Swapped MFMA (A = U', B = x), mu*S folded into Tf'. One barrier total.
// LDS = 40960 B exactly; __launch_bounds__(512,8) pins VGPR<=64 -> 4 blocks/CU,
// grid 1024 = one full round (no tail).
__global__ __launch_bounds__(512, 8) void att1_main(
    const float* __restrict__ emb, const short* __restrict__ afrag,
    const float* __restrict__ Tf, const float* __restrict__ c2a,
    const float* __restrict__ consts, const float* __restrict__ ai,
    const float* __restrict__ aj, float* __restrict__ out)
{
    __shared__ float xb_s[128 * XST];      // 34816 B
    __shared__ float scWS[8][128];         // 4096 B (scores -> alphas in place)
    __shared__ float ajcWS[8][64];         // 2048 B (aj + c2, per wave)

    const int tid = threadIdx.x, lane = tid & 63, w = tid >> 6;
    const int b = blockIdx.y;
    const int p = blockIdx.x * 8 + w;
    const int bp = b * 128 + p;
    const float* embB = emb + b * 8192;

    // stage emb[b] into LDS (stride 68)
    {
        const int r0 = tid >> 4, c0 = (tid & 15) * 4;
        #pragma unroll
        for (int pass = 0; pass < 4; ++pass) {
            int r = r0 + pass * 32;
            *(float4*)&xb_s[r * XST + c0] = *(const float4*)&embB[r * 64 + c0];
        }
    }
    __syncthreads();   // the only block barrier

    // per-wave ajc table (same-wave write->read, no barrier needed)
    ajcWS[w][lane] = aj[(size_t)bp * 64 + lane] + c2a[lane];

    const int g4 = lane >> 4, dl = lane & 15;
    const float sw2b2 = consts[0];

    // --- stats (wave-private, registers): lane does q = lane and q = lane+64
    float rsa, rsb;
    {
        const float* xpr = &xb_s[p * XST];
        const float* xqa = &xb_s[lane * XST];
        const float* xqb = &xb_s[(64 + lane) * XST];
        float sa = 0.f, sa2 = 0.f, sb = 0.f, sb2 = 0.f;
        #pragma unroll
        for (int j = 0; j < 16; ++j) {
            float4 a = *(const float4*)(xpr + 4 * j);
            float4 qa = *(const float4*)(xqa + 4 * j);
            float4 qb = *(const float4*)(xqb + 4 * j);
            float a0 = a.x * qa.x, a1 = a.y * qa.y, a2 = a.z * qa.z, a3 = a.w * qa.w;
            sa += a0 + a1 + a2 + a3;
            sa2 = fmaf(a0, a0, fmaf(a1, a1, fmaf(a2, a2, fmaf(a3, a3, sa2))));
            float b0 = a.x * qb.x, b1v = a.y * qb.y, b2v = a.z * qb.z, b3 = a.w * qb.w;
            sb += b0 + b1v + b2v + b3;
            sb2 = fmaf(b0, b0, fmaf(b1v, b1v, fmaf(b2v, b2v, fmaf(b3, b3, sb2))));
        }
        float ma = sa * (1.f / 64.f);
        float va = fmaxf(sa2 * (1.f / 64.f) - ma * ma, 0.f);
        rsa = rsqrtf(va + LN_EPS) * S2LE;
        float mb = sb * (1.f / 64.f);
        float vb = fmaxf(sb2 * (1.f / 64.f) - mb * mb, 0.f);
        rsb = rsqrtf(vb + LN_EPS) * S2LE;
    }

    // --- A-build (wave-private): U'[d][k] = x_p[k] * T'[d,k]
    bf16x8 bfr[4][2];
    #pragma unroll
    for (int h = 0; h < 2; ++h) {
        const float* xr = &xb_s[p * XST + 32 * h + 8 * g4];
        float4 x0 = *(const float4*)xr, x1 = *(const float4*)(xr + 4);
        #pragma unroll
        for (int dt = 0; dt < 4; ++dt) {
            const float4* tf = (const float4*)(Tf + (size_t)((dt * 2 + h) * 64 + lane) * 8);
            float4 t0 = tf[0], t1 = tf[1];
            float4 u0 = {t0.x * x0.x, t0.y * x0.y, t0.z * x0.z, t0.w * x0.w};
            float4 u1 = {t1.x * x1.x, t1.y * x1.y, t1.z * x1.z, t1.w * x1.w};
            bfr[dt][h] = pack8(u0, u1);
        }
    }

    // per-lane ai base: row q = 16qt + dl, cols 4g4 + 16dt (L2-hot)
    const float* ai_ln = ai + ((size_t)(b * 128) + dl) * 64 + 4 * g4;
    const short* afb = afrag + (size_t)(b * 16) * 512 + lane * 8;
    const float* ajcW = &ajcWS[w][0];
    const float* w2g = consts + 16;

    // --- q-tile loop. Lane's q = 16*qt + dl for ALL its 16 elements.
    #pragma unroll 1
    for (int qt = 0; qt < 8; ++qt) {
        bf16x8 afr0 = *(const bf16x8*)(afb + (size_t)(2 * qt + 0) * 512);
        bf16x8 afr1 = *(const bf16x8*)(afb + (size_t)(2 * qt + 1) * 512);

        // rs via shuffle from the lane that computed q's stats
        float rsel = (qt < 4) ? rsa : rsb;
        float rsv = __shfl(rsel, (16 * qt + dl) & 63, 64);
        const float* aiq = ai_ln + (size_t)qt * 1024;
        float pr = 0.f;

        // half 0: dt = 0,1
        {
            f32x4 a0 = {0.f, 0.f, 0.f, 0.f}, a1 = {0.f, 0.f, 0.f, 0.f};
            a0 = __builtin_amdgcn_mfma_f32_16x16x32_bf16(bfr[0][0], afr0, a0, 0, 0, 0);
            a0 = __builtin_amdgcn_mfma_f32_16x16x32_bf16(bfr[0][1], afr1, a0, 0, 0, 0);
            a1 = __builtin_amdgcn_mfma_f32_16x16x32_bf16(bfr[1][0], afr0, a1, 0, 0, 0);
            a1 = __builtin_amdgcn_mfma_f32_16x16x32_bf16(bfr[1][1], afr1, a1, 0, 0, 0);
            pr = epi4(a0, rsv, aiq + 0,  ajcW, w2g, 4 * g4, pr);
            pr = epi4(a1, rsv, aiq + 16, ajcW, w2g, 16 + 4 * g4, pr);
        }
        // half 1: dt = 2,3 (acc registers reused)
        {
            f32x4 a0 = {0.f, 0.f, 0.f, 0.f}, a1 = {0.f, 0.f, 0.f, 0.f};
            a0 = __builtin_amdgcn_mfma_f32_16x16x32_bf16(bfr[2][0], afr0, a0, 0, 0, 0);
            a0 = __builtin_amdgcn_mfma_f32_16x16x32_bf16(bfr[2][1], afr1, a0, 0, 0, 0);
            a1 = __builtin_amdgcn_mfma_f32_16x16x32_bf16(bfr[3][0], afr0, a1, 0, 0, 0);
            a1 = __builtin_amdgcn_mfma_f32_16x16x32_bf16(bfr[3][1], afr1, a1, 0, 0, 0);
            pr = epi4(a0, rsv, aiq + 32, ajcW, w2g, 32 + 4 * g4, pr);
            pr = epi4(a1, rsv, aiq + 48, ajcW, w2g, 48 + 4 * g4, pr);
        }

        pr += __shfl_xor(pr, 16, 64);
        pr += __shfl_xor(pr, 32, 64);
        if (lane < 16) scWS[w][16 * qt + lane] = pr + sw2b2;
    }

    // --- softmax (wave-private; alphas overwrite scores in place)
    {
        float s0 = scWS[w][lane], s1 = scWS[w][64 + lane];
        float M = wmax(fmaxf(s0, s1));
        float e0 = fexp2((s0 - M) * L2E), e1 = fexp2((s1 - M) * L2E);
        float rZ = frcp(wsum(e0 + e1));
        scWS[w][lane] = e0 * rZ;
        scWS[w][64 + lane] = e1 * rZ;
    }

    // --- ctx: lane owns d-quad 4*dl, q-subset {4i + g4}
    {
        const int d0 = 4 * dl;
        float4 S1 = {0.f, 0.f, 0.f, 0.f}, S2 = {0.f, 0.f, 0.f, 0.f};
        #pragma unroll 8
        for (int i = 0; i < 32; ++i) {
            int q = 4 * i + g4;
            float al = scWS[w][q];
            float4 xq = *(const float4*)&xb_s[q * XST + d0];
            S1.x = fmaf(al, xq.x, S1.x); S1.y = fmaf(al, xq.y, S1.y);
            S1.z = fmaf(al, xq.z, S1.z); S1.w = fmaf(al, xq.w, S1.w);
            S2.x = fmaf(al, fabsf(xq.x), S2.x); S2.y = fmaf(al, fabsf(xq.y), S2.y);
            S2.z = fmaf(al, fabsf(xq.z), S2.z); S2.w = fmaf(al, fabsf(xq.w), S2.w);
        }
        #pragma unroll
        for (int off = 16; off <= 32; off <<= 1) {
            S1.x += __shfl_xor(S1.x, off, 64); S1.y += __shfl_xor(S1.y, off, 64);
            S1.z += __shfl_xor(S1.z, off, 64); S1.w += __shfl_xor(S1.w, off, 64);
            S2.x += __shfl_xor(S2.x, off, 64); S2.y += __shfl_xor(S2.y, off, 64);
            S2.z += __shfl_xor(S2.z, off, 64); S2.w += __shfl_xor(S2.w, off, 64);
        }
        if (g4 == 0) {
            float4 xp4 = *(const float4*)&xb_s[p * XST + d0];
            float4 o;
            o.x = fmaf(0.505f * xp4.x, S1.x, 0.495f * fabsf(xp4.x) * S2.x);
            o.y = fmaf(0.505f * xp4.y, S1.y, 0.495f * fabsf(xp4.y) * S2.y);
            o.z = fmaf(0.505f * xp4.z, S1.z, 0.495f * fabsf(xp4.z) * S2.z);
            o.w = fmaf(0.505f * xp4.w, S1.w, 0.495f * fabsf(xp4.w) * S2.w);
            *(float4*)&out[(size_t)bp * 64 + d0] = o;
        }
    }
}

extern "C" void kernel_launch(void* const* d_in, const int* in_sizes, int n_in,
                              void* d_out, int out_size, void* d_ws, size_t ws_size,
                              hipStream_t stream) {
    const float* emb = (const float*)d_in[0];   // [64,128,64]
    const float* g   = (const float*)d_in[1];   // [64]
    const float* bln = (const float*)d_in[2];   // [64]
    const float* W1  = (const float*)d_in[3];   // [192,64]
    const float* b1  = (const float*)d_in[4];   // [64]
    const float* W2  = (const float*)d_in[5];   // [64,1]
    const float* b2  = (const float*)d_in[6];   // [1]
    float* out = (float*)d_out;

    float* ws = (float*)d_ws;
    float* ai = ws;                      // 524288 f
    float* aj = ws + 524288;             // 524288 f
    float* Tf = ws + 1048576;            // 4096 f
    float* c2 = ws + 1052672;            // 64 f
    float* consts = ws + 1052736;        // 128 f ([0]=sum(W2)+b2, [16..79]=-2*W2)
    short* af = (short*)(ws + 1052864);  // 524288 bf16 (1 MB)

    att1_prep<<<513, 256, 0, stream>>>(emb, g, bln, W1, b1, W2, b2,
                                       ai, aj, af, Tf, c2, consts);
    att1_main<<<dim3(16, 64), 512, 0, stream>>>(emb, af, Tf, c2, consts,
                                                ai, aj, out);
}

// Round 11
// 78.174 us; speedup vs baseline: 1.6237x; 1.6237x over previous
//
#include <hip/hip_runtime.h>
#include <hip/hip_bf16.h>

#define LN_EPS 1e-5f
#define S2LE 2.885390081777927f   // 2*log2(e)
#define L2E  1.4426950408889634f  // log2(e)
#define XST 68                    // LDS row stride for x tile (16B-aligned rows)

typedef __attribute__((ext_vector_type(8))) short bf16x8;
typedef __attribute__((ext_vector_type(4))) float f32x4;

__device__ __forceinline__ float wsum(float v) {
    #pragma unroll
    for (int off = 32; off; off >>= 1) v += __shfl_xor(v, off, 64);
    return v;
}
__device__ __forceinline__ float wmax(float v) {
    #pragma unroll
    for (int off = 32; off; off >>= 1) v = fmaxf(v, __shfl_xor(v, off, 64));
    return v;
}
// 8x f32 -> bf16 (RNE) via v_cvt_pk_bf16_f32
__device__ __forceinline__ bf16x8 pack8(float4 a, float4 b) {
    __hip_bfloat162 h0 = __float22bfloat162_rn(float2{a.x, a.y});
    __hip_bfloat162 h1 = __float22bfloat162_rn(float2{a.z, a.w});
    __hip_bfloat162 h2 = __float22bfloat162_rn(float2{b.x, b.y});
    __hip_bfloat162 h3 = __float22bfloat162_rn(float2{b.z, b.w});
    short2 s0 = *reinterpret_cast<short2*>(&h0);
    short2 s1 = *reinterpret_cast<short2*>(&h1);
    short2 s2 = *reinterpret_cast<short2*>(&h2);
    short2 s3 = *reinterpret_cast<short2*>(&h3);
    bf16x8 r;
    r[0] = s0.x; r[1] = s0.y; r[2] = s1.x; r[3] = s1.y;
    r[4] = s2.x; r[5] = s2.y; r[6] = s3.x; r[7] = s3.y;
    return r;
}
__device__ __forceinline__ float fexp2(float x) {
#if __has_builtin(__builtin_amdgcn_exp2f)
    return __builtin_amdgcn_exp2f(x);
#else
    return exp2f(x);
#endif
}
__device__ __forceinline__ float frcp(float x) {
#if __has_builtin(__builtin_amdgcn_rcpf)
    return __builtin_amdgcn_rcpf(x);
#else
    return 1.f / x;
#endif
}

// ================= prep: 513 blocks x 256 threads, roles by blockIdx =================
// blocks 0..255   : ai/aj (32 rows each), prescaled by S2LE
// blocks 256..511 : afrag pack (4 fragment-slots per block)
// block 512       : Tf' = g*Wij - S/64 (A-frag order), c2, consts[0]=sum(W2)+b2,
//                   consts[16+d] = -2*W2[d]
__global__ __launch_bounds__(256) void att1_prep(
    const float* __restrict__ emb, const float* __restrict__ g,
    const float* __restrict__ bln, const float* __restrict__ W1,
    const float* __restrict__ b1, const float* __restrict__ W2,
    const float* __restrict__ b2, float* __restrict__ ai,
    float* __restrict__ aj, short* __restrict__ afrag,
    float* __restrict__ Tf, float* __restrict__ c2, float* __restrict__ consts)
{
    const int bid = blockIdx.x, tid = threadIdx.x, lane = tid & 63, wid = tid >> 6;
    if (bid < 256) {
        __shared__ float w_s[8192];
        __shared__ float xn_s[4][64];
        for (int i = tid * 4; i < 8192; i += 1024)
            *(float4*)&w_s[i] = *(const float4*)&W1[i];
        __syncthreads();
        #pragma unroll 2
        for (int it = 0; it < 8; ++it) {
            const int r = bid * 32 + it * 4 + wid;
            float x = emb[r * 64 + lane];
            float m = wsum(x) * (1.f / 64.f);
            float xc = x - m;
            float var = wsum(xc * xc) * (1.f / 64.f);
            float xn = xc * rsqrtf(var + LN_EPS) * g[lane] + bln[lane];
            xn_s[wid][lane] = xn;          // same-wave write->read
            float a0 = 0.f, a1 = 0.f;
            #pragma unroll
            for (int k = 0; k < 64; ++k) {
                float xnk = xn_s[wid][k];
                a0 = fmaf(xnk, w_s[k * 64 + lane], a0);
                a1 = fmaf(xnk, w_s[(64 + k) * 64 + lane], a1);
            }
            ai[r * 64 + lane] = a0 * S2LE;
            aj[r * 64 + lane] = a1 * S2LE;
        }
    } else if (bid < 512) {
        const int id = (bid - 256) * 4 + wid;      // b*16 + qt*2 + h
        const int h = id & 1, qt = (id >> 1) & 7, bb = id >> 4;
        const int q = 16 * qt + (lane & 15);
        const int k = 32 * h + 8 * (lane >> 4);
        const float* src = emb + (bb * 128 + q) * 64 + k;
        float4 v0 = ((const float4*)src)[0];
        float4 v1 = ((const float4*)src)[1];
        *(bf16x8*)(afrag + (size_t)(id * 64 + lane) * 8) = pack8(v0, v1);
    } else {
        __shared__ float S_s[64];
        if (tid < 64) {
            float S = 0.f, c = 0.f;
            for (int k = 0; k < 64; ++k) {
                float w = W1[(128 + k) * 64 + tid];
                S = fmaf(g[k], w, S);
                c = fmaf(bln[k], w, c);
            }
            S_s[tid] = S * (1.f / 64.f);
            c2[tid] = (c + b1[tid]) * S2LE;
            consts[16 + tid] = -2.f * W2[tid];
            if (tid == 0) {
                float sw = 0.f;
                for (int d = 0; d < 64; ++d) sw += W2[d];
                consts[0] = sw + b2[0];
            }
        }
        __syncthreads();
        for (int slot = tid; slot < 512; slot += 256) {   // (dt*2+h)*64 + l
            int l = slot & 63, h = (slot >> 6) & 1, dt = slot >> 7;
            int n = 16 * dt + (l & 15);                   // A-frag row = d
            int k = 32 * h + 8 * (l >> 4);
            float Sn = S_s[n];                            // S[d]/64
            #pragma unroll
            for (int j = 0; j < 8; ++j)
                Tf[slot * 8 + j] = fmaf(g[k + j], W1[(128 + k + j) * 64 + n], -Sn);
        }
    }
}

// ================= main: block = (b, 8 p's), 512 thr; wave w owns p = 8*bx + w.
// Swapped MFMA (A = U', B = x), mu*S folded into Tf'. dt OUTER (8-reg frag pair),
// qt inner unrolled, pr[8] accumulates across dt. Demand ~51 VGPR -> 64-tier,
// LDS 40960 B -> 4 blocks/CU x 8 waves; grid 1024 = one round.
__global__ __launch_bounds__(512) void att1_main(
    const float* __restrict__ emb, const short* __restrict__ afrag,
    const float* __restrict__ Tf, const float* __restrict__ c2a,
    const float* __restrict__ consts, const float* __restrict__ ai,
    const float* __restrict__ aj, float* __restrict__ out)
{
    __shared__ float xb_s[128 * XST];      // 34816 B
    __shared__ float scWS[8][128];         // 4096 B (scores -> alphas in place)
    __shared__ float ajcWS[8][64];         // 2048 B (aj + c2, per wave)

    const int tid = threadIdx.x, lane = tid & 63, w = tid >> 6;
    const int b = blockIdx.y;
    const int p = blockIdx.x * 8 + w;
    const int bp = b * 128 + p;
    const float* embB = emb + b * 8192;

    // stage emb[b] into LDS (stride 68)
    {
        const int r0 = tid >> 4, c0 = (tid & 15) * 4;
        #pragma unroll
        for (int pass = 0; pass < 4; ++pass) {
            int r = r0 + pass * 32;
            *(float4*)&xb_s[r * XST + c0] = *(const float4*)&embB[r * 64 + c0];
        }
    }
    __syncthreads();   // the only block barrier

    // per-wave ajc table (same-wave write->read, no barrier needed)
    ajcWS[w][lane] = aj[(size_t)bp * 64 + lane] + c2a[lane];

    const int g4 = lane >> 4, dl = lane & 15;
    const float sw2b2 = consts[0];

    // --- stats (wave-private, registers): lane does q = lane and q = lane+64
    float rsa, rsb;
    {
        const float* xpr = &xb_s[p * XST];
        const float* xqa = &xb_s[lane * XST];
        const float* xqb = &xb_s[(64 + lane) * XST];
        float sa = 0.f, sa2 = 0.f, sb = 0.f, sb2 = 0.f;
        #pragma unroll
        for (int j = 0; j < 16; ++j) {
            float4 a = *(const float4*)(xpr + 4 * j);
            float4 qa = *(const float4*)(xqa + 4 * j);
            float4 qb = *(const float4*)(xqb + 4 * j);
            float a0 = a.x * qa.x, a1 = a.y * qa.y, a2 = a.z * qa.z, a3 = a.w * qa.w;
            sa += a0 + a1 + a2 + a3;
            sa2 = fmaf(a0, a0, fmaf(a1, a1, fmaf(a2, a2, fmaf(a3, a3, sa2))));
            float b0 = a.x * qb.x, b1v = a.y * qb.y, b2v = a.z * qb.z, b3 = a.w * qb.w;
            sb += b0 + b1v + b2v + b3;
            sb2 = fmaf(b0, b0, fmaf(b1v, b1v, fmaf(b2v, b2v, fmaf(b3, b3, sb2))));
        }
        float ma = sa * (1.f / 64.f);
        float va = fmaxf(sa2 * (1.f / 64.f) - ma * ma, 0.f);
        rsa = rsqrtf(va + LN_EPS) * S2LE;
        float mb = sb * (1.f / 64.f);
        float vb = fmaxf(sb2 * (1.f / 64.f) - mb * mb, 0.f);
        rsb = rsqrtf(vb + LN_EPS) * S2LE;
    }

    // per-lane bases (loop-invariant)
    const float* ai_ln = ai + ((size_t)(b * 128) + dl) * 64 + 4 * g4;
    const short* afb = afrag + (size_t)(b * 16) * 512 + lane * 8;
    const float* ajcW = &ajcWS[w][0];
    const float* w2g = consts + 16;
    const float* tfb = Tf + lane * 8;
    const float* xpb = &xb_s[p * XST + 8 * g4];

    float pr[8] = {0.f, 0.f, 0.f, 0.f, 0.f, 0.f, 0.f, 0.f};

    // --- dt OUTER (rolled: one 8-reg fragment pair live), qt inner (unrolled)
    #pragma unroll 1
    for (int dt = 0; dt < 4; ++dt) {
        // build this dt's U' fragment pair (h = 0, 1)
        bf16x8 bh0, bh1;
        {
            float4 x0 = *(const float4*)xpb;
            float4 x1 = *(const float4*)(xpb + 4);
            const float4* tf = (const float4*)(tfb + (size_t)(dt * 2) * 512);
            float4 t0 = tf[0], t1 = tf[1];
            float4 u0 = {t0.x * x0.x, t0.y * x0.y, t0.z * x0.z, t0.w * x0.w};
            float4 u1 = {t1.x * x1.x, t1.y * x1.y, t1.z * x1.z, t1.w * x1.w};
            bh0 = pack8(u0, u1);
            float4 y0 = *(const float4*)(xpb + 32);
            float4 y1 = *(const float4*)(xpb + 36);
            const float4* tg = (const float4*)(tfb + (size_t)(dt * 2 + 1) * 512);
            float4 s0 = tg[0], s1 = tg[1];
            float4 v0 = {s0.x * y0.x, s0.y * y0.y, s0.z * y0.z, s0.w * y0.w};
            float4 v1 = {s1.x * y1.x, s1.y * y1.y, s1.z * y1.z, s1.w * y1.w};
            bh1 = pack8(v0, v1);
        }

        const float4 ajc4 = *(const float4*)(ajcW + dt * 16 + 4 * g4);
        const float4 w24  = *(const float4*)(w2g + dt * 16 + 4 * g4);
        const float ajcv[4] = {ajc4.x, ajc4.y, ajc4.z, ajc4.w};
        const float w2v[4]  = {w24.x, w24.y, w24.z, w24.w};

        #pragma unroll
        for (int qt = 0; qt < 8; ++qt) {
            bf16x8 afr0 = *(const bf16x8*)(afb + (size_t)(2 * qt + 0) * 512);
            bf16x8 afr1 = *(const bf16x8*)(afb + (size_t)(2 * qt + 1) * 512);
            f32x4 a = {0.f, 0.f, 0.f, 0.f};
            a = __builtin_amdgcn_mfma_f32_16x16x32_bf16(bh0, afr0, a, 0, 0, 0);
            a = __builtin_amdgcn_mfma_f32_16x16x32_bf16(bh1, afr1, a, 0, 0, 0);

            float rsel = (qt < 4) ? rsa : rsb;
            float rsv = __shfl(rsel, (16 * qt + dl) & 63, 64);

            float4 aif = *(const float4*)(ai_ln + (size_t)qt * 1024 + dt * 16);
            float aiv[4] = {aif.x, aif.y, aif.z, aif.w};
            float s = pr[qt];
            #pragma unroll
            for (int r = 0; r < 4; ++r) {
                float xv = fmaf(rsv, a[r], ajcv[r] + aiv[r]);
                float e = fexp2(xv);
                s = fmaf(w2v[r], frcp(e + 1.f), s);
            }
            pr[qt] = s;
        }
    }

    // reduce pr across the 4 d-groups and publish scores
    #pragma unroll
    for (int qt = 0; qt < 8; ++qt) {
        float v = pr[qt];
        v += __shfl_xor(v, 16, 64);
        v += __shfl_xor(v, 32, 64);
        if (lane < 16) scWS[w][16 * qt + lane] = v + sw2b2;
    }

    // --- softmax (wave-private; alphas overwrite scores in place)
    {
        float s0 = scWS[w][lane], s1 = scWS[w][64 + lane];
        float M = wmax(fmaxf(s0, s1));
        float e0 = fexp2((s0 - M) * L2E), e1 = fexp2((s1 - M) * L2E);
        float rZ = frcp(wsum(e0 + e1));
        scWS[w][lane] = e0 * rZ;
        scWS[w][64 + lane] = e1 * rZ;
    }

    // --- ctx: lane owns d-quad 4*dl, q-subset {4i + g4}
    {
        const int d0 = 4 * dl;
        float4 S1 = {0.f, 0.f, 0.f, 0.f}, S2 = {0.f, 0.f, 0.f, 0.f};
        #pragma unroll 8
        for (int i = 0; i < 32; ++i) {
            int q = 4 * i + g4;
            float al = scWS[w][q];
            float4 xq = *(const float4*)&xb_s[q * XST + d0];
            S1.x = fmaf(al, xq.x, S1.x); S1.y = fmaf(al, xq.y, S1.y);
            S1.z = fmaf(al, xq.z, S1.z); S1.w = fmaf(al, xq.w, S1.w);
            S2.x = fmaf(al, fabsf(xq.x), S2.x); S2.y = fmaf(al, fabsf(xq.y), S2.y);
            S2.z = fmaf(al, fabsf(xq.z), S2.z); S2.w = fmaf(al, fabsf(xq.w), S2.w);
        }
        #pragma unroll
        for (int off = 16; off <= 32; off <<= 1) {
            S1.x += __shfl_xor(S1.x, off, 64); S1.y += __shfl_xor(S1.y, off, 64);
            S1.z += __shfl_xor(S1.z, off, 64); S1.w += __shfl_xor(S1.w, off, 64);
            S2.x += __shfl_xor(S2.x, off, 64); S2.y += __shfl_xor(S2.y, off, 64);
            S2.z += __shfl_xor(S2.z, off, 64); S2.w += __shfl_xor(S2.w, off, 64);
        }
        if (g4 == 0) {
            float4 xp4 = *(const float4*)&xb_s[p * XST + d0];
            float4 o;
            o.x = fmaf(0.505f * xp4.x, S1.x, 0.495f * fabsf(xp4.x) * S2.x);
            o.y = fmaf(0.505f * xp4.y, S1.y, 0.495f * fabsf(xp4.y) * S2.y);
            o.z = fmaf(0.505f * xp4.z, S1.z, 0.495f * fabsf(xp4.z) * S2.z);
            o.w = fmaf(0.505f * xp4.w, S1.w, 0.495f * fabsf(xp4.w) * S2.w);
            *(float4*)&out[(size_t)bp * 64 + d0] = o;
        }
    }
}

extern "C" void kernel_launch(void* const* d_in, const int* in_sizes, int n_in,
                              void* d_out, int out_size, void* d_ws, size_t ws_size,
                              hipStream_t stream) {
    const float* emb = (const float*)d_in[0];   // [64,128,64]
    const float* g   = (const float*)d_in[1];   // [64]
    const float* bln = (const float*)d_in[2];   // [64]
    const float* W1  = (const float*)d_in[3];   // [192,64]
    const float* b1  = (const float*)d_in[4];   // [64]
    const float* W2  = (const float*)d_in[5];   // [64,1]
    const float* b2  = (const float*)d_in[6];   // [1]
    float* out = (float*)d_out;

    float* ws = (float*)d_ws;
    float* ai = ws;                      // 524288 f
    float* aj = ws + 524288;             // 524288 f
    float* Tf = ws + 1048576;            // 4096 f
    float* c2 = ws + 1052672;            // 64 f
    float* consts = ws + 1052736;        // 128 f ([0]=sum(W2)+b2, [16..79]=-2*W2)
    short* af = (short*)(ws + 1052864);  // 524288 bf16 (1 MB)

    att1_prep<<<513, 256, 0, stream>>>(emb, g, bln, W1, b1, W2, b2,
                                       ai, aj, af, Tf, c2, consts);
    att1_main<<<dim3(16, 64), 512, 0, stream>>>(emb, af, Tf, c2, consts,
                                                ai, aj, out);
}

// Round 12
// 71.919 us; speedup vs baseline: 1.7649x; 1.0870x over previous
//
#include <hip/hip_runtime.h>
#include <hip/hip_bf16.h>

#define LN_EPS 1e-5f
#define S2LE 2.885390081777927f   // 2*log2(e)
#define L2E  1.4426950408889634f  // log2(e)
#define XST 68                    // LDS row stride for x tile (16B-aligned rows)

typedef __attribute__((ext_vector_type(8))) short bf16x8;
typedef __attribute__((ext_vector_type(4))) float f32x4;

__device__ __forceinline__ float wsum(float v) {
    #pragma unroll
    for (int off = 32; off; off >>= 1) v += __shfl_xor(v, off, 64);
    return v;
}
__device__ __forceinline__ float wmax(float v) {
    #pragma unroll
    for (int off = 32; off; off >>= 1) v = fmaxf(v, __shfl_xor(v, off, 64));
    return v;
}
// 8x f32 -> bf16 (RNE) via v_cvt_pk_bf16_f32
__device__ __forceinline__ bf16x8 pack8(float4 a, float4 b) {
    __hip_bfloat162 h0 = __float22bfloat162_rn(float2{a.x, a.y});
    __hip_bfloat162 h1 = __float22bfloat162_rn(float2{a.z, a.w});
    __hip_bfloat162 h2 = __float22bfloat162_rn(float2{b.x, b.y});
    __hip_bfloat162 h3 = __float22bfloat162_rn(float2{b.z, b.w});
    short2 s0 = *reinterpret_cast<short2*>(&h0);
    short2 s1 = *reinterpret_cast<short2*>(&h1);
    short2 s2 = *reinterpret_cast<short2*>(&h2);
    short2 s3 = *reinterpret_cast<short2*>(&h3);
    bf16x8 r;
    r[0] = s0.x; r[1] = s0.y; r[2] = s1.x; r[3] = s1.y;
    r[4] = s2.x; r[5] = s2.y; r[6] = s3.x; r[7] = s3.y;
    return r;
}
__device__ __forceinline__ float fexp2(float x) {
#if __has_builtin(__builtin_amdgcn_exp2f)
    return __builtin_amdgcn_exp2f(x);
#else
    return exp2f(x);
#endif
}
__device__ __forceinline__ float frcp(float x) {
#if __has_builtin(__builtin_amdgcn_rcpf)
    return __builtin_amdgcn_rcpf(x);
#else
    return 1.f / x;
#endif
}

// ================= prep: 513 blocks x 256 threads, roles by blockIdx =================
// blocks 0..255   : ai/aj (32 rows each), prescaled by S2LE
// blocks 256..511 : afrag pack (4 fragment-slots per block)
// block 512       : Tf' = g*Wij - S/64 (A-frag order), c2, consts[0]=sum(W2)+b2,
//                   consts[16+d] = -2*W2[d]
__global__ __launch_bounds__(256) void att1_prep(
    const float* __restrict__ emb, const float* __restrict__ g,
    const float* __restrict__ bln, const float* __restrict__ W1,
    const float* __restrict__ b1, const float* __restrict__ W2,
    const float* __restrict__ b2, float* __restrict__ ai,
    float* __restrict__ aj, short* __restrict__ afrag,
    float* __restrict__ Tf, float* __restrict__ c2, float* __restrict__ consts)
{
    const int bid = blockIdx.x, tid = threadIdx.x, lane = tid & 63, wid = tid >> 6;
    if (bid < 256) {
        __shared__ float w_s[8192];
        __shared__ float xn_s[4][64];
        for (int i = tid * 4; i < 8192; i += 1024)
            *(float4*)&w_s[i] = *(const float4*)&W1[i];
        __syncthreads();
        #pragma unroll 2
        for (int it = 0; it < 8; ++it) {
            const int r = bid * 32 + it * 4 + wid;
            float x = emb[r * 64 + lane];
            float m = wsum(x) * (1.f / 64.f);
            float xc = x - m;
            float var = wsum(xc * xc) * (1.f / 64.f);
            float xn = xc * rsqrtf(var + LN_EPS) * g[lane] + bln[lane];
            xn_s[wid][lane] = xn;          // same-wave write->read
            float a0 = 0.f, a1 = 0.f;
            #pragma unroll
            for (int k = 0; k < 64; ++k) {
                float xnk = xn_s[wid][k];
                a0 = fmaf(xnk, w_s[k * 64 + lane], a0);
                a1 = fmaf(xnk, w_s[(64 + k) * 64 + lane], a1);
            }
            ai[r * 64 + lane] = a0 * S2LE;
            aj[r * 64 + lane] = a1 * S2LE;
        }
    } else if (bid < 512) {
        const int id = (bid - 256) * 4 + wid;      // b*16 + qt*2 + h
        const int h = id & 1, qt = (id >> 1) & 7, bb = id >> 4;
        const int q = 16 * qt + (lane & 15);
        const int k = 32 * h + 8 * (lane >> 4);
        const float* src = emb + (bb * 128 + q) * 64 + k;
        float4 v0 = ((const float4*)src)[0];
        float4 v1 = ((const float4*)src)[1];
        *(bf16x8*)(afrag + (size_t)(id * 64 + lane) * 8) = pack8(v0, v1);
    } else {
        __shared__ float S_s[64];
        if (tid < 64) {
            float S = 0.f, c = 0.f;
            for (int k = 0; k < 64; ++k) {
                float w = W1[(128 + k) * 64 + tid];
                S = fmaf(g[k], w, S);
                c = fmaf(bln[k], w, c);
            }
            S_s[tid] = S * (1.f / 64.f);
            c2[tid] = (c + b1[tid]) * S2LE;
            consts[16 + tid] = -2.f * W2[tid];
            if (tid == 0) {
                float sw = 0.f;
                for (int d = 0; d < 64; ++d) sw += W2[d];
                consts[0] = sw + b2[0];
            }
        }
        __syncthreads();
        for (int slot = tid; slot < 512; slot += 256) {   // (dt*2+h)*64 + l
            int l = slot & 63, h = (slot >> 6) & 1, dt = slot >> 7;
            int n = 16 * dt + (l & 15);                   // A-frag row = d
            int k = 32 * h + 8 * (l >> 4);
            float Sn = S_s[n];                            // S[d]/64
            #pragma unroll
            for (int j = 0; j < 8; ++j)
                Tf[slot * 8 + j] = fmaf(g[k + j], W1[(128 + k + j) * 64 + n], -Sn);
        }
    }
}

// per-dt epilogue quad: pr += sum_r w2[r] / (2^xv + 1) terms
__device__ __forceinline__ float epi4(f32x4 acc, float rsv, const float* aiq,
                                      const float* ajcW, const float* w2g,
                                      int off, float pr) {
    float4 ajc4 = *(const float4*)(ajcW + off);
    float4 w24  = *(const float4*)(w2g + off);
    float4 aif  = *(const float4*)aiq;
    float ajcv[4] = {ajc4.x, ajc4.y, ajc4.z, ajc4.w};
    float w2v[4]  = {w24.x, w24.y, w24.z, w24.w};
    float aiv[4]  = {aif.x, aif.y, aif.z, aif.w};
    #pragma unroll
    for (int r = 0; r < 4; ++r) {
        float xv = fmaf(rsv, acc[r], ajcv[r] + aiv[r]);
        float e = fexp2(xv);
        pr = fmaf(w2v[r], frcp(e + 1.f), pr);
    }
    return pr;
}

// ================= main: block = (b, 8 p's), 512 thr; wave w owns p = 8*bx + w.
// Swapped MFMA (A = U', B = x), mu*S folded into Tf'. acc split in 2 halves
// (8 acc VGPRs reused) -> demand ~60. Plain launch_bounds: allocator free.
// LDS = 40960 B exactly -> 4 blocks/CU; grid 1024 = one full round.
__global__ __launch_bounds__(512) void att1_main(
    const float* __restrict__ emb, const short* __restrict__ afrag,
    const float* __restrict__ Tf, const float* __restrict__ c2a,
    const float* __restrict__ consts, const float* __restrict__ ai,
    const float* __restrict__ aj, float* __restrict__ out)
{
    __shared__ float xb_s[128 * XST];      // 34816 B
    __shared__ float scWS[8][128];         // 4096 B (scores -> alphas in place)
    __shared__ float ajcWS[8][64];         // 2048 B (aj + c2, per wave)

    const int tid = threadIdx.x, lane = tid & 63, w = tid >> 6;
    const int b = blockIdx.y;
    const int p = blockIdx.x * 8 + w;
    const int bp = b * 128 + p;
    const float* embB = emb + b * 8192;

    // stage emb[b] into LDS (stride 68)
    {
        const int r0 = tid >> 4, c0 = (tid & 15) * 4;
        #pragma unroll
        for (int pass = 0; pass < 4; ++pass) {
            int r = r0 + pass * 32;
            *(float4*)&xb_s[r * XST + c0] = *(const float4*)&embB[r * 64 + c0];
        }
    }
    __syncthreads();   // the only block barrier

    // per-wave ajc table (same-wave write->read, no barrier needed)
    ajcWS[w][lane] = aj[(size_t)bp * 64 + lane] + c2a[lane];

    const int g4 = lane >> 4, dl = lane & 15;
    const float sw2b2 = consts[0];

    // --- stats (wave-private, registers): lane does q = lane and q = lane+64
    float rsa, rsb;
    {
        const float* xpr = &xb_s[p * XST];
        const float* xqa = &xb_s[lane * XST];
        const float* xqb = &xb_s[(64 + lane) * XST];
        float sa = 0.f, sa2 = 0.f, sb = 0.f, sb2 = 0.f;
        #pragma unroll
        for (int j = 0; j < 16; ++j) {
            float4 a = *(const float4*)(xpr + 4 * j);
            float4 qa = *(const float4*)(xqa + 4 * j);
            float4 qb = *(const float4*)(xqb + 4 * j);
            float a0 = a.x * qa.x, a1 = a.y * qa.y, a2 = a.z * qa.z, a3 = a.w * qa.w;
            sa += a0 + a1 + a2 + a3;
            sa2 = fmaf(a0, a0, fmaf(a1, a1, fmaf(a2, a2, fmaf(a3, a3, sa2))));
            float b0 = a.x * qb.x, b1v = a.y * qb.y, b2v = a.z * qb.z, b3 = a.w * qb.w;
            sb += b0 + b1v + b2v + b3;
            sb2 = fmaf(b0, b0, fmaf(b1v, b1v, fmaf(b2v, b2v, fmaf(b3, b3, sb2))));
        }
        float ma = sa * (1.f / 64.f);
        float va = fmaxf(sa2 * (1.f / 64.f) - ma * ma, 0.f);
        rsa = rsqrtf(va + LN_EPS) * S2LE;
        float mb = sb * (1.f / 64.f);
        float vb = fmaxf(sb2 * (1.f / 64.f) - mb * mb, 0.f);
        rsb = rsqrtf(vb + LN_EPS) * S2LE;
    }

    // --- A-build (wave-private): U'[d][k] = x_p[k] * T'[d,k]
    bf16x8 bfr[4][2];
    #pragma unroll
    for (int h = 0; h < 2; ++h) {
        const float* xr = &xb_s[p * XST + 32 * h + 8 * g4];
        float4 x0 = *(const float4*)xr, x1 = *(const float4*)(xr + 4);
        #pragma unroll
        for (int dt = 0; dt < 4; ++dt) {
            const float4* tf = (const float4*)(Tf + (size_t)((dt * 2 + h) * 64 + lane) * 8);
            float4 t0 = tf[0], t1 = tf[1];
            float4 u0 = {t0.x * x0.x, t0.y * x0.y, t0.z * x0.z, t0.w * x0.w};
            float4 u1 = {t1.x * x1.x, t1.y * x1.y, t1.z * x1.z, t1.w * x1.w};
            bfr[dt][h] = pack8(u0, u1);
        }
    }

    // per-lane ai base: row q = 16qt + dl, cols 4g4 + 16dt (L2-hot)
    const float* ai_ln = ai + ((size_t)(b * 128) + dl) * 64 + 4 * g4;
    const short* afb = afrag + (size_t)(b * 16) * 512 + lane * 8;
    const float* ajcW = &ajcWS[w][0];
    const float* w2g = consts + 16;

    // --- q-tile loop. Lane's q = 16*qt + dl for ALL its 16 elements.
    #pragma unroll 1
    for (int qt = 0; qt < 8; ++qt) {
        bf16x8 afr0 = *(const bf16x8*)(afb + (size_t)(2 * qt + 0) * 512);
        bf16x8 afr1 = *(const bf16x8*)(afb + (size_t)(2 * qt + 1) * 512);

        // rs via shuffle from the lane that computed q's stats
        float rsel = (qt < 4) ? rsa : rsb;
        float rsv = __shfl(rsel, (16 * qt + dl) & 63, 64);
        const float* aiq = ai_ln + (size_t)qt * 1024;
        float pr = 0.f;

        // half 0: dt = 0,1
        {
            f32x4 a0 = {0.f, 0.f, 0.f, 0.f}, a1 = {0.f, 0.f, 0.f, 0.f};
            a0 = __builtin_amdgcn_mfma_f32_16x16x32_bf16(bfr[0][0], afr0, a0, 0, 0, 0);
            a0 = __builtin_amdgcn_mfma_f32_16x16x32_bf16(bfr[0][1], afr1, a0, 0, 0, 0);
            a1 = __builtin_amdgcn_mfma_f32_16x16x32_bf16(bfr[1][0], afr0, a1, 0, 0, 0);
            a1 = __builtin_amdgcn_mfma_f32_16x16x32_bf16(bfr[1][1], afr1, a1, 0, 0, 0);
            pr = epi4(a0, rsv, aiq + 0,  ajcW, w2g, 4 * g4, pr);
            pr = epi4(a1, rsv, aiq + 16, ajcW, w2g, 16 + 4 * g4, pr);
        }
        // half 1: dt = 2,3 (acc registers reused)
        {
            f32x4 a0 = {0.f, 0.f, 0.f, 0.f}, a1 = {0.f, 0.f, 0.f, 0.f};
            a0 = __builtin_amdgcn_mfma_f32_16x16x32_bf16(bfr[2][0], afr0, a0, 0, 0, 0);
            a0 = __builtin_amdgcn_mfma_f32_16x16x32_bf16(bfr[2][1], afr1, a0, 0, 0, 0);
            a1 = __builtin_amdgcn_mfma_f32_16x16x32_bf16(bfr[3][0], afr0, a1, 0, 0, 0);
            a1 = __builtin_amdgcn_mfma_f32_16x16x32_bf16(bfr[3][1], afr1, a1, 0, 0, 0);
            pr = epi4(a0, rsv, aiq + 32, ajcW, w2g, 32 + 4 * g4, pr);
            pr = epi4(a1, rsv, aiq + 48, ajcW, w2g, 48 + 4 * g4, pr);
        }

        pr += __shfl_xor(pr, 16, 64);
        pr += __shfl_xor(pr, 32, 64);
        if (lane < 16) scWS[w][16 * qt + lane] = pr + sw2b2;
    }

    // --- softmax (wave-private; alphas overwrite scores in place)
    {
        float s0 = scWS[w][lane], s1 = scWS[w][64 + lane];
        float M = wmax(fmaxf(s0, s1));
        float e0 = fexp2((s0 - M) * L2E), e1 = fexp2((s1 - M) * L2E);
        float rZ = frcp(wsum(e0 + e1));
        scWS[w][lane] = e0 * rZ;
        scWS[w][64 + lane] = e1 * rZ;
    }

    // --- ctx: lane owns d-quad 4*dl, q-subset {4i + g4}
    {
        const int d0 = 4 * dl;
        float4 S1 = {0.f, 0.f, 0.f, 0.f}, S2 = {0.f, 0.f, 0.f, 0.f};
        #pragma unroll 8
        for (int i = 0; i < 32; ++i) {
            int q = 4 * i + g4;
            float al = scWS[w][q];
            float4 xq = *(const float4*)&xb_s[q * XST + d0];
            S1.x = fmaf(al, xq.x, S1.x); S1.y = fmaf(al, xq.y, S1.y);
            S1.z = fmaf(al, xq.z, S1.z); S1.w = fmaf(al, xq.w, S1.w);
            S2.x = fmaf(al, fabsf(xq.x), S2.x); S2.y = fmaf(al, fabsf(xq.y), S2.y);
            S2.z = fmaf(al, fabsf(xq.z), S2.z); S2.w = fmaf(al, fabsf(xq.w), S2.w);
        }
        #pragma unroll
        for (int off = 16; off <= 32; off <<= 1) {
            S1.x += __shfl_xor(S1.x, off, 64); S1.y += __shfl_xor(S1.y, off, 64);
            S1.z += __shfl_xor(S1.z, off, 64); S1.w += __shfl_xor(S1.w, off, 64);
            S2.x += __shfl_xor(S2.x, off, 64); S2.y += __shfl_xor(S2.y, off, 64);
            S2.z += __shfl_xor(S2.z, off, 64); S2.w += __shfl_xor(S2.w, off, 64);
        }
        if (g4 == 0) {
            float4 xp4 = *(const float4*)&xb_s[p * XST + d0];
            float4 o;
            o.x = fmaf(0.505f * xp4.x, S1.x, 0.495f * fabsf(xp4.x) * S2.x);
            o.y = fmaf(0.505f * xp4.y, S1.y, 0.495f * fabsf(xp4.y) * S2.y);
            o.z = fmaf(0.505f * xp4.z, S1.z, 0.495f * fabsf(xp4.z) * S2.z);
            o.w = fmaf(0.505f * xp4.w, S1.w, 0.495f * fabsf(xp4.w) * S2.w);
            *(float4*)&out[(size_t)bp * 64 + d0] = o;
        }
    }
}

extern "C" void kernel_launch(void* const* d_in, const int* in_sizes, int n_in,
                              void* d_out, int out_size, void* d_ws, size_t ws_size,
                              hipStream_t stream) {
    const float* emb = (const float*)d_in[0];   // [64,128,64]
    const float* g   = (const float*)d_in[1];   // [64]
    const float* bln = (const float*)d_in[2];   // [64]
    const float* W1  = (const float*)d_in[3];   // [192,64]
    const float* b1  = (const float*)d_in[4];   // [64]
    const float* W2  = (const float*)d_in[5];   // [64,1]
    const float* b2  = (const float*)d_in[6];   // [1]
    float* out = (float*)d_out;

    float* ws = (float*)d_ws;
    float* ai = ws;                      // 524288 f
    float* aj = ws + 524288;             // 524288 f
    float* Tf = ws + 1048576;            // 4096 f
    float* c2 = ws + 1052672;            // 64 f
    float* consts = ws + 1052736;        // 128 f ([0]=sum(W2)+b2, [16..79]=-2*W2)
    short* af = (short*)(ws + 1052864);  // 524288 bf16 (1 MB)

    att1_prep<<<513, 256, 0, stream>>>(emb, g, bln, W1, b1, W2, b2,
                                       ai, aj, af, Tf, c2, consts);
    att1_main<<<dim3(16, 64), 512, 0, stream>>>(emb, af, Tf, c2, consts,
                                                ai, aj, out);
}

// Round 13
// 64.688 us; speedup vs baseline: 1.9622x; 1.1118x over previous
//
#include <hip/hip_runtime.h>
#include <hip/hip_bf16.h>

#define LN_EPS 1e-5f
#define S2LE 2.885390081777927f   // 2*log2(e)
#define L2E  1.4426950408889634f  // log2(e)
#define XST 68                    // LDS row stride for x tile (16B-aligned rows)

typedef __attribute__((ext_vector_type(8))) short bf16x8;
typedef __attribute__((ext_vector_type(4))) float f32x4;

__device__ __forceinline__ float wsum(float v) {
    #pragma unroll
    for (int off = 32; off; off >>= 1) v += __shfl_xor(v, off, 64);
    return v;
}
__device__ __forceinline__ float wmax(float v) {
    #pragma unroll
    for (int off = 32; off; off >>= 1) v = fmaxf(v, __shfl_xor(v, off, 64));
    return v;
}
// 8x f32 -> bf16 (RNE) via v_cvt_pk_bf16_f32
__device__ __forceinline__ bf16x8 pack8(float4 a, float4 b) {
    __hip_bfloat162 h0 = __float22bfloat162_rn(float2{a.x, a.y});
    __hip_bfloat162 h1 = __float22bfloat162_rn(float2{a.z, a.w});
    __hip_bfloat162 h2 = __float22bfloat162_rn(float2{b.x, b.y});
    __hip_bfloat162 h3 = __float22bfloat162_rn(float2{b.z, b.w});
    short2 s0 = *reinterpret_cast<short2*>(&h0);
    short2 s1 = *reinterpret_cast<short2*>(&h1);
    short2 s2 = *reinterpret_cast<short2*>(&h2);
    short2 s3 = *reinterpret_cast<short2*>(&h3);
    bf16x8 r;
    r[0] = s0.x; r[1] = s0.y; r[2] = s1.x; r[3] = s1.y;
    r[4] = s2.x; r[5] = s2.y; r[6] = s3.x; r[7] = s3.y;
    return r;
}
__device__ __forceinline__ float fexp2(float x) {
#if __has_builtin(__builtin_amdgcn_exp2f)
    return __builtin_amdgcn_exp2f(x);
#else
    return exp2f(x);
#endif
}
__device__ __forceinline__ float frcp(float x) {
#if __has_builtin(__builtin_amdgcn_rcpf)
    return __builtin_amdgcn_rcpf(x);
#else
    return 1.f / x;
#endif
}

// ================= prep: 513 blocks x 256 threads, roles by blockIdx =================
// blocks 0..255   : ai/aj (32 rows each), prescaled by S2LE
// blocks 256..511 : afrag pack (4 fragment-slots per block)
// block 512       : Tf' = g*Wij - S/64 (A-frag order), c2, consts[16+d] = -2*W2[d]
__global__ __launch_bounds__(256) void att1_prep(
    const float* __restrict__ emb, const float* __restrict__ g,
    const float* __restrict__ bln, const float* __restrict__ W1,
    const float* __restrict__ b1, const float* __restrict__ W2,
    const float* __restrict__ b2, float* __restrict__ ai,
    float* __restrict__ aj, short* __restrict__ afrag,
    float* __restrict__ Tf, float* __restrict__ c2, float* __restrict__ consts)
{
    const int bid = blockIdx.x, tid = threadIdx.x, lane = tid & 63, wid = tid >> 6;
    if (bid < 256) {
        __shared__ float w_s[8192];
        __shared__ float xn_s[4][64];
        for (int i = tid * 4; i < 8192; i += 1024)
            *(float4*)&w_s[i] = *(const float4*)&W1[i];
        __syncthreads();
        #pragma unroll 2
        for (int it = 0; it < 8; ++it) {
            const int r = bid * 32 + it * 4 + wid;
            float x = emb[r * 64 + lane];
            float m = wsum(x) * (1.f / 64.f);
            float xc = x - m;
            float var = wsum(xc * xc) * (1.f / 64.f);
            float xn = xc * rsqrtf(var + LN_EPS) * g[lane] + bln[lane];
            xn_s[wid][lane] = xn;          // same-wave write->read
            float a0 = 0.f, a1 = 0.f;
            #pragma unroll
            for (int k = 0; k < 64; ++k) {
                float xnk = xn_s[wid][k];
                a0 = fmaf(xnk, w_s[k * 64 + lane], a0);
                a1 = fmaf(xnk, w_s[(64 + k) * 64 + lane], a1);
            }
            ai[r * 64 + lane] = a0 * S2LE;
            aj[r * 64 + lane] = a1 * S2LE;
        }
    } else if (bid < 512) {
        const int id = (bid - 256) * 4 + wid;      // b*16 + qt*2 + h
        const int h = id & 1, qt = (id >> 1) & 7, bb = id >> 4;
        const int q = 16 * qt + (lane & 15);
        const int k = 32 * h + 8 * (lane >> 4);
        const float* src = emb + (bb * 128 + q) * 64 + k;
        float4 v0 = ((const float4*)src)[0];
        float4 v1 = ((const float4*)src)[1];
        *(bf16x8*)(afrag + (size_t)(id * 64 + lane) * 8) = pack8(v0, v1);
    } else {
        __shared__ float S_s[64];
        if (tid < 64) {
            float S = 0.f, c = 0.f;
            for (int k = 0; k < 64; ++k) {
                float w = W1[(128 + k) * 64 + tid];
                S = fmaf(g[k], w, S);
                c = fmaf(bln[k], w, c);
            }
            S_s[tid] = S * (1.f / 64.f);
            c2[tid] = (c + b1[tid]) * S2LE;
            consts[16 + tid] = -2.f * W2[tid];
        }
        __syncthreads();
        for (int slot = tid; slot < 512; slot += 256) {   // (dt*2+h)*64 + l
            int l = slot & 63, h = (slot >> 6) & 1, dt = slot >> 7;
            int n = 16 * dt + (l & 15);                   // A-frag row = d
            int k = 32 * h + 8 * (l >> 4);
            float Sn = S_s[n];                            // S[d]/64
            #pragma unroll
            for (int j = 0; j < 8; ++j)
                Tf[slot * 8 + j] = fmaf(g[k + j], W1[(128 + k + j) * 64 + n], -Sn);
        }
    }
}

// per-dt epilogue quad: pr += sum_r w2[r] / (2^xv + 1) terms
__device__ __forceinline__ float epi4(f32x4 acc, float rsv, const float* aiq,
                                      const float* ajcW, const float* w2g,
                                      int off, float pr) {
    float4 ajc4 = *(const float4*)(ajcW + off);
    float4 w24  = *(const float4*)(w2g + off);
    float4 aif  = *(const float4*)aiq;
    float ajcv[4] = {ajc4.x, ajc4.y, ajc4.z, ajc4.w};
    float w2v[4]  = {w24.x, w24.y, w24.z, w24.w};
    float aiv[4]  = {aif.x, aif.y, aif.z, aif.w};
    #pragma unroll
    for (int r = 0; r < 4; ++r) {
        float xv = fmaf(rsv, acc[r], ajcv[r] + aiv[r]);
        float e = fexp2(xv);
        pr = fmaf(w2v[r], frcp(e + 1.f), pr);
    }
    return pr;
}

// ================= main: block = (b, 8 p's), 512 thr; wave w owns p = 8*bx + w.
// Swapped MFMA (A = U', B = x), mu*S folded into Tf'. Register diet vs r12:
// (1) sum(W2)+b2 dropped (softmax shift-invariant), (2) rs staged through scWS
// (read rsv from LDS, overwrite with score in same iteration; wave DS ordering).
// LDS = 40960 B exactly -> 4 blocks/CU; grid 1024 = one round at 64-VGPR tier.
__global__ __launch_bounds__(512) void att1_main(
    const float* __restrict__ emb, const short* __restrict__ afrag,
    const float* __restrict__ Tf, const float* __restrict__ c2a,
    const float* __restrict__ consts, const float* __restrict__ ai,
    const float* __restrict__ aj, float* __restrict__ out)
{
    __shared__ float xb_s[128 * XST];      // 34816 B
    __shared__ float scWS[8][128];         // 4096 B (rs -> scores -> alphas in place)
    __shared__ float ajcWS[8][64];         // 2048 B (aj + c2, per wave)

    const int tid = threadIdx.x, lane = tid & 63, w = tid >> 6;
    const int b = blockIdx.y;
    const int p = blockIdx.x * 8 + w;
    const int bp = b * 128 + p;
    const float* embB = emb + b * 8192;

    // stage emb[b] into LDS (stride 68)
    {
        const int r0 = tid >> 4, c0 = (tid & 15) * 4;
        #pragma unroll
        for (int pass = 0; pass < 4; ++pass) {
            int r = r0 + pass * 32;
            *(float4*)&xb_s[r * XST + c0] = *(const float4*)&embB[r * 64 + c0];
        }
    }
    __syncthreads();   // the only block barrier

    // per-wave ajc table (same-wave write->read, no barrier needed)
    ajcWS[w][lane] = aj[(size_t)bp * 64 + lane] + c2a[lane];

    const int g4 = lane >> 4, dl = lane & 15;

    // --- stats: lane does q = lane and q = lane+64; rs written straight to scWS
    {
        const float* xpr = &xb_s[p * XST];
        const float* xqa = &xb_s[lane * XST];
        const float* xqb = &xb_s[(64 + lane) * XST];
        float sa = 0.f, sa2 = 0.f, sb = 0.f, sb2 = 0.f;
        #pragma unroll
        for (int j = 0; j < 16; ++j) {
            float4 a = *(const float4*)(xpr + 4 * j);
            float4 qa = *(const float4*)(xqa + 4 * j);
            float4 qb = *(const float4*)(xqb + 4 * j);
            float a0 = a.x * qa.x, a1 = a.y * qa.y, a2 = a.z * qa.z, a3 = a.w * qa.w;
            sa += a0 + a1 + a2 + a3;
            sa2 = fmaf(a0, a0, fmaf(a1, a1, fmaf(a2, a2, fmaf(a3, a3, sa2))));
            float b0 = a.x * qb.x, b1v = a.y * qb.y, b2v = a.z * qb.z, b3 = a.w * qb.w;
            sb += b0 + b1v + b2v + b3;
            sb2 = fmaf(b0, b0, fmaf(b1v, b1v, fmaf(b2v, b2v, fmaf(b3, b3, sb2))));
        }
        float ma = sa * (1.f / 64.f);
        float va = fmaxf(sa2 * (1.f / 64.f) - ma * ma, 0.f);
        scWS[w][lane] = rsqrtf(va + LN_EPS) * S2LE;
        float mb = sb * (1.f / 64.f);
        float vb = fmaxf(sb2 * (1.f / 64.f) - mb * mb, 0.f);
        scWS[w][64 + lane] = rsqrtf(vb + LN_EPS) * S2LE;
    }

    // --- A-build (wave-private): U'[d][k] = x_p[k] * T'[d,k]
    bf16x8 bfr[4][2];
    #pragma unroll
    for (int h = 0; h < 2; ++h) {
        const float* xr = &xb_s[p * XST + 32 * h + 8 * g4];
        float4 x0 = *(const float4*)xr, x1 = *(const float4*)(xr + 4);
        #pragma unroll
        for (int dt = 0; dt < 4; ++dt) {
            const float4* tf = (const float4*)(Tf + (size_t)((dt * 2 + h) * 64 + lane) * 8);
            float4 t0 = tf[0], t1 = tf[1];
            float4 u0 = {t0.x * x0.x, t0.y * x0.y, t0.z * x0.z, t0.w * x0.w};
            float4 u1 = {t1.x * x1.x, t1.y * x1.y, t1.z * x1.z, t1.w * x1.w};
            bfr[dt][h] = pack8(u0, u1);
        }
    }

    // per-lane ai base: row q = 16qt + dl, cols 4g4 + 16dt (L2-hot)
    const float* ai_ln = ai + ((size_t)(b * 128) + dl) * 64 + 4 * g4;
    const short* afb = afrag + (size_t)(b * 16) * 512 + lane * 8;
    const float* ajcW = &ajcWS[w][0];
    const float* w2g = consts + 16;

    // --- q-tile loop. Lane's q = 16*qt + dl for ALL its 16 elements.
    // rsv read from scWS, then the same 16 entries are overwritten with the score
    // (wave-internal DS ops execute in order -> no hazard, no barrier).
    #pragma unroll 1
    for (int qt = 0; qt < 8; ++qt) {
        bf16x8 afr0 = *(const bf16x8*)(afb + (size_t)(2 * qt + 0) * 512);
        bf16x8 afr1 = *(const bf16x8*)(afb + (size_t)(2 * qt + 1) * 512);

        float rsv = scWS[w][16 * qt + dl];
        const float* aiq = ai_ln + (size_t)qt * 1024;
        float pr = 0.f;

        // half 0: dt = 0,1
        {
            f32x4 a0 = {0.f, 0.f, 0.f, 0.f}, a1 = {0.f, 0.f, 0.f, 0.f};
            a0 = __builtin_amdgcn_mfma_f32_16x16x32_bf16(bfr[0][0], afr0, a0, 0, 0, 0);
            a0 = __builtin_amdgcn_mfma_f32_16x16x32_bf16(bfr[0][1], afr1, a0, 0, 0, 0);
            a1 = __builtin_amdgcn_mfma_f32_16x16x32_bf16(bfr[1][0], afr0, a1, 0, 0, 0);
            a1 = __builtin_amdgcn_mfma_f32_16x16x32_bf16(bfr[1][1], afr1, a1, 0, 0, 0);
            pr = epi4(a0, rsv, aiq + 0,  ajcW, w2g, 4 * g4, pr);
            pr = epi4(a1, rsv, aiq + 16, ajcW, w2g, 16 + 4 * g4, pr);
        }
        // half 1: dt = 2,3 (acc registers reused)
        {
            f32x4 a0 = {0.f, 0.f, 0.f, 0.f}, a1 = {0.f, 0.f, 0.f, 0.f};
            a0 = __builtin_amdgcn_mfma_f32_16x16x32_bf16(bfr[2][0], afr0, a0, 0, 0, 0);
            a0 = __builtin_amdgcn_mfma_f32_16x16x32_bf16(bfr[2][1], afr1, a0, 0, 0, 0);
            a1 = __builtin_amdgcn_mfma_f32_16x16x32_bf16(bfr[3][0], afr0, a1, 0, 0, 0);
            a1 = __builtin_amdgcn_mfma_f32_16x16x32_bf16(bfr[3][1], afr1, a1, 0, 0, 0);
            pr = epi4(a0, rsv, aiq + 32, ajcW, w2g, 32 + 4 * g4, pr);
            pr = epi4(a1, rsv, aiq + 48, ajcW, w2g, 48 + 4 * g4, pr);
        }

        pr += __shfl_xor(pr, 16, 64);
        pr += __shfl_xor(pr, 32, 64);
        if (lane < 16) scWS[w][16 * qt + lane] = pr;
    }

    // --- softmax (wave-private; alphas overwrite scores in place).
    // Constant term sum(W2)+b2 omitted from scores: softmax is shift-invariant.
    {
        float s0 = scWS[w][lane], s1 = scWS[w][64 + lane];
        float M = wmax(fmaxf(s0, s1));
        float e0 = fexp2((s0 - M) * L2E), e1 = fexp2((s1 - M) * L2E);
        float rZ = frcp(wsum(e0 + e1));
        scWS[w][lane] = e0 * rZ;
        scWS[w][64 + lane] = e1 * rZ;
    }

    // --- ctx: lane owns d-quad 4*dl, q-subset {4i + g4}
    {
        const int d0 = 4 * dl;
        float4 S1 = {0.f, 0.f, 0.f, 0.f}, S2 = {0.f, 0.f, 0.f, 0.f};
        #pragma unroll 8
        for (int i = 0; i < 32; ++i) {
            int q = 4 * i + g4;
            float al = scWS[w][q];
            float4 xq = *(const float4*)&xb_s[q * XST + d0];
            S1.x = fmaf(al, xq.x, S1.x); S1.y = fmaf(al, xq.y, S1.y);
            S1.z = fmaf(al, xq.z, S1.z); S1.w = fmaf(al, xq.w, S1.w);
            S2.x = fmaf(al, fabsf(xq.x), S2.x); S2.y = fmaf(al, fabsf(xq.y), S2.y);
            S2.z = fmaf(al, fabsf(xq.z), S2.z); S2.w = fmaf(al, fabsf(xq.w), S2.w);
        }
        #pragma unroll
        for (int off = 16; off <= 32; off <<= 1) {
            S1.x += __shfl_xor(S1.x, off, 64); S1.y += __shfl_xor(S1.y, off, 64);
            S1.z += __shfl_xor(S1.z, off, 64); S1.w += __shfl_xor(S1.w, off, 64);
            S2.x += __shfl_xor(S2.x, off, 64); S2.y += __shfl_xor(S2.y, off, 64);
            S2.z += __shfl_xor(S2.z, off, 64); S2.w += __shfl_xor(S2.w, off, 64);
        }
        if (g4 == 0) {
            float4 xp4 = *(const float4*)&xb_s[p * XST + d0];
            float4 o;
            o.x = fmaf(0.505f * xp4.x, S1.x, 0.495f * fabsf(xp4.x) * S2.x);
            o.y = fmaf(0.505f * xp4.y, S1.y, 0.495f * fabsf(xp4.y) * S2.y);
            o.z = fmaf(0.505f * xp4.z, S1.z, 0.495f * fabsf(xp4.z) * S2.z);
            o.w = fmaf(0.505f * xp4.w, S1.w, 0.495f * fabsf(xp4.w) * S2.w);
            *(float4*)&out[(size_t)bp * 64 + d0] = o;
        }
    }
}

extern "C" void kernel_launch(void* const* d_in, const int* in_sizes, int n_in,
                              void* d_out, int out_size, void* d_ws, size_t ws_size,
                              hipStream_t stream) {
    const float* emb = (const float*)d_in[0];   // [64,128,64]
    const float* g   = (const float*)d_in[1];   // [64]
    const float* bln = (const float*)d_in[2];   // [64]
    const float* W1  = (const float*)d_in[3];   // [192,64]
    const float* b1  = (const float*)d_in[4];   // [64]
    const float* W2  = (const float*)d_in[5];   // [64,1]
    const float* b2  = (const float*)d_in[6];   // [1]
    float* out = (float*)d_out;

    float* ws = (float*)d_ws;
    float* ai = ws;                      // 524288 f
    float* aj = ws + 524288;             // 524288 f
    float* Tf = ws + 1048576;            // 4096 f
    float* c2 = ws + 1052672;            // 64 f
    float* consts = ws + 1052736;        // 128 f ([16..79] = -2*W2)
    short* af = (short*)(ws + 1052864);  // 524288 bf16 (1 MB)

    att1_prep<<<513, 256, 0, stream>>>(emb, g, bln, W1, b1, W2, b2,
                                       ai, aj, af, Tf, c2, consts);
    att1_main<<<dim3(16, 64), 512, 0, stream>>>(emb, af, Tf, c2, consts,
                                                ai, aj, out);
}